// Round 2
// baseline (2199.481 us; speedup 1.0000x reference)
//
#include <hip/hip_runtime.h>

#define T_NT 4
#define T_R  5
#define T_H  4
#define T_DK 32
#define T_HD 128
#define T_L  2

typedef unsigned short u16;

__device__ __forceinline__ float bf2f(u16 u){
  union { float f; unsigned int i; } v; v.i = ((unsigned int)u) << 16; return v.f;
}
__device__ __forceinline__ u16 f2bf(float f){
  union { float f; unsigned int i; } v; v.f = f;
  unsigned int x = v.i;
  return (u16)((x + 0x7fffu + ((x >> 16) & 1u)) >> 16);
}
__device__ __forceinline__ float gelu_f(float x){
  float x3 = x*x*x;
  return 0.5f * x * (1.f + tanhf(0.7978845608028654f * (x + 0.044715f * x3)));
}

// ---------------- CSR / bucket build ----------------
__global__ void k_hist(const int* __restrict__ key, int* __restrict__ cnt, int n){
  int i = blockIdx.x*256 + threadIdx.x;
  if (i < n) atomicAdd(&cnt[key[i]], 1);
}
__global__ void k_toff(const int* __restrict__ cnt, int* __restrict__ off){
  if (threadIdx.x == 0){
    off[0] = 0;
    for (int t = 0; t < T_NT; ++t) off[t+1] = off[t] + cnt[t];
  }
}
__global__ void k_scan(const int* __restrict__ deg, int* __restrict__ rp, int n){
  __shared__ int buf[1024];
  __shared__ int carry_s;
  int tid = threadIdx.x;
  if (tid == 0) carry_s = 0;
  __syncthreads();
  for (int base = 0; base < n; base += 1024){
    int v = (base + tid < n) ? deg[base + tid] : 0;
    buf[tid] = v;
    __syncthreads();
    for (int off = 1; off < 1024; off <<= 1){
      int add = (tid >= off) ? buf[tid - off] : 0;
      __syncthreads();
      buf[tid] += add;
      __syncthreads();
    }
    int c = carry_s;
    if (base + tid < n) rp[base + tid] = c + buf[tid] - v;
    __syncthreads();
    if (tid == 0) carry_s = c + buf[1023];
    __syncthreads();
  }
  if (tid == 0) rp[n] = carry_s;
}
__global__ void k_copy(const int* __restrict__ a, int* __restrict__ b, int n){
  int i = blockIdx.x*256 + threadIdx.x;
  if (i < n) b[i] = a[i];
}
__global__ void k_scatter_nodes(const int* __restrict__ nt, const int* __restrict__ off,
                                int* __restrict__ cur, int* __restrict__ perm, int n){
  int i = blockIdx.x*256 + threadIdx.x;
  if (i < n){
    int t = nt[i];
    int p = atomicAdd(&cur[t], 1);
    perm[off[t] + p] = i;
  }
}
__global__ void k_fill_edges(const int* __restrict__ srcp, const int* __restrict__ dstp,
                             const int* __restrict__ etp, int* __restrict__ cur,
                             int* __restrict__ packed, int n){
  int i = blockIdx.x*256 + threadIdx.x;
  if (i < n){
    int d = dstp[i];
    int p = atomicAdd(&cur[d], 1);
    packed[p] = srcp[i] | (etp[i] << 17);   // N=50000 < 2^17
  }
}

// ---------------- per-type gathered GEMM (f32 in, f32 weights, fp32 accum) ----------------
// MODE: 0 plain, 1 tanh epilogue (adapt), 3 gelu-on-input + gated residual (update)
// OB: 1 -> out bf16 (u16), 0 -> out f32
template<int MODE, int OB>
__global__ __launch_bounds__(256)
void k_typed_gemm(const float* __restrict__ X,
                  const int* __restrict__ tperm, const int* __restrict__ toff,
                  const float* __restrict__ W, const float* __restrict__ Bi,
                  void* __restrict__ outv,
                  const float* __restrict__ h_in, const float* __restrict__ skipv)
{
  int t = blockIdx.y;
  int lo = toff[t], cnt = toff[t+1] - lo;
  int base = (int)blockIdx.x * 64;
  if (base >= cnt) return;
  __shared__ float As[64][16];
  __shared__ float Bs[16][128];
  __shared__ int rows_s[64];
  int tid = threadIdx.x;
  if (tid < 64){
    int m = base + tid;
    rows_s[tid] = (m < cnt) ? tperm[lo + m] : -1;
  }
  __syncthreads();
  float acc[8][4];
#pragma unroll
  for (int i=0;i<8;i++){ acc[i][0]=0.f;acc[i][1]=0.f;acc[i][2]=0.f;acc[i][3]=0.f; }
  int ty = tid >> 5, tx = tid & 31;
  const float* Wt = W + (size_t)t * (T_HD*T_HD);
  for (int k0 = 0; k0 < T_HD; k0 += 16){
#pragma unroll
    for (int j=0;j<4;j++){
      int idx = tid + j*256;
      int m = idx >> 4, kk = idx & 15;
      int row = rows_s[m];
      float v = 0.f;
      if (row >= 0){
        v = X[(size_t)row*T_HD + k0 + kk];
        if (MODE == 3) v = gelu_f(v);
      }
      As[m][kk] = v;
    }
#pragma unroll
    for (int j=0;j<8;j++){
      int idx = tid + j*256;
      int kk = idx >> 7, c = idx & 127;
      Bs[kk][c] = Wt[(size_t)(k0+kk)*T_HD + c];
    }
    __syncthreads();
#pragma unroll
    for (int kk=0;kk<16;kk++){
      float4 bv = *(const float4*)&Bs[kk][tx*4];
#pragma unroll
      for (int i=0;i<8;i++){
        float a = As[ty*8+i][kk];
        acc[i][0] += a*bv.x; acc[i][1] += a*bv.y; acc[i][2] += a*bv.z; acc[i][3] += a*bv.w;
      }
    }
    __syncthreads();
  }
  float sk = 0.f;
  if (MODE == 3) sk = 1.f / (1.f + __expf(-skipv[t]));
#pragma unroll
  for (int i=0;i<8;i++){
    int m = ty*8 + i;
    int row = rows_s[m];
    if (row < 0) continue;
#pragma unroll
    for (int q=0;q<4;q++){
      int c = tx*4 + q;
      float vv = acc[i][q] + Bi[t*T_HD + c];
      if (MODE == 1) vv = tanhf(vv);
      if (MODE == 3) vv = vv*sk + h_in[(size_t)row*T_HD + c]*(1.f - sk);
      if (OB) ((u16*)outv)[(size_t)row*T_HD + c] = f2bf(vv);
      else    ((float*)outv)[(size_t)row*T_HD + c] = vv;
    }
  }
}

// ---------------- per-node block-diagonal transform ----------------
// TR=1 (qt): out[n,r,h,i] = sum_j X[n,h*32+j] * Wg[r,h,i,j]
// TR=0 (mtp): out[n,r,h,j] = sum_i X[n,h*32+i] * Wg[r,h,i,j]
template<int TR>
__global__ __launch_bounds__(256)
void k_blockdiag(const u16* __restrict__ X, const float* __restrict__ Wg,
                 u16* __restrict__ Y, int n)
{
  int r = blockIdx.y;
  int base = (int)blockIdx.x * 64;
  if (base >= n) return;
  __shared__ float Xs[64][T_H][33];
  __shared__ float Ws[T_H * 1032];   // per-head stride 1032 (bank spread)
  int tid = threadIdx.x;
  for (int idx = tid; idx < T_H*T_DK*T_DK; idx += 256){
    int o = idx & 31, c = (idx >> 5) & 31, h = idx >> 10;
    float wv;
    if (TR) wv = Wg[(((size_t)r*T_H + h)*T_DK + o)*T_DK + c];
    else    wv = Wg[(((size_t)r*T_H + h)*T_DK + c)*T_DK + o];
    Ws[h*1032 + c*32 + o] = wv;
  }
  for (int idx = tid; idx < 64*T_HD; idx += 256){
    int mm = idx >> 7, cc = idx & 127;
    int row = base + mm;
    Xs[mm][cc >> 5][cc & 31] = (row < n) ? bf2f(X[(size_t)row*T_HD + cc]) : 0.f;
  }
  __syncthreads();
  int ty = tid >> 5, tx = tid & 31;
  int h = tx >> 3, ob = tx & 7;
  float acc[8][4];
#pragma unroll
  for (int i=0;i<8;i++){ acc[i][0]=0.f;acc[i][1]=0.f;acc[i][2]=0.f;acc[i][3]=0.f; }
  const float* Wh = &Ws[h*1032];
#pragma unroll
  for (int c=0;c<T_DK;c++){
    float w0 = Wh[c*32 + ob];
    float w1 = Wh[c*32 + ob + 8];
    float w2 = Wh[c*32 + ob + 16];
    float w3 = Wh[c*32 + ob + 24];
#pragma unroll
    for (int i=0;i<8;i++){
      float x = Xs[ty*8+i][h][c];
      acc[i][0] += x*w0; acc[i][1] += x*w1; acc[i][2] += x*w2; acc[i][3] += x*w3;
    }
  }
#pragma unroll
  for (int i=0;i<8;i++){
    int row = base + ty*8 + i;
    if (row < n){
      size_t rb = (size_t)row*(T_R*T_HD) + (size_t)r*T_HD + h*32 + ob;
      Y[rb]      = f2bf(acc[i][0]);
      Y[rb + 8]  = f2bf(acc[i][1]);
      Y[rb + 16] = f2bf(acc[i][2]);
      Y[rb + 24] = f2bf(acc[i][3]);
    }
  }
}

// ---------------- per-dst edge attention (one wave per dst, online softmax) ----------------
__global__ __launch_bounds__(256)
void k_edge_attn(const u16* __restrict__ kB, const u16* __restrict__ qt,
                 const u16* __restrict__ mtp, const int* __restrict__ rp,
                 const int* __restrict__ packed, const float* __restrict__ pri,
                 float* __restrict__ resb, int n)
{
  int lane = threadIdx.x & 63;
  int wid = (int)blockIdx.x * (blockDim.x >> 6) + (threadIdx.x >> 6);
  int nw = (int)gridDim.x * (blockDim.x >> 6);
  int h1 = lane >> 5;           // head of first half: 0/1; second half head = h1+2
  const float isd = 0.17677669529663687f;
  float pr1[T_R], pr2[T_R];
#pragma unroll
  for (int r=0;r<T_R;r++){
    pr1[r] = pri[r*T_H + h1] * isd;
    pr2[r] = pri[r*T_H + h1 + 2] * isd;
  }
  for (int dst = wid; dst < n; dst += nw){
    int e0 = rp[dst], e1 = rp[dst+1];
    size_t qbase = (size_t)dst * (T_R*T_HD);
    float u1[T_R], u2[T_R];
#pragma unroll
    for (int r=0;r<T_R;r++){
      u1[r] = bf2f(qt[qbase + r*T_HD + lane]);
      u2[r] = bf2f(qt[qbase + r*T_HD + 64 + lane]);
    }
    float m1=-INFINITY, m2=-INFINITY, d1=0.f, d2=0.f, a1=0.f, a2=0.f;
    for (int ei=e0; ei<e1; ++ei){
      int pk = packed[ei];
      int s = pk & 131071;
      int rt = pk >> 17;
      float ka = bf2f(kB[(size_t)s*T_HD + lane]);
      float kb = bf2f(kB[(size_t)s*T_HD + 64 + lane]);
      float ua, ub, pa, pb;
      switch(rt){
        case 0: ua=u1[0]; ub=u2[0]; pa=pr1[0]; pb=pr2[0]; break;
        case 1: ua=u1[1]; ub=u2[1]; pa=pr1[1]; pb=pr2[1]; break;
        case 2: ua=u1[2]; ub=u2[2]; pa=pr1[2]; pb=pr2[2]; break;
        case 3: ua=u1[3]; ub=u2[3]; pa=pr1[3]; pb=pr2[3]; break;
        default:ua=u1[4]; ub=u2[4]; pa=pr1[4]; pb=pr2[4]; break;
      }
      float p1 = ua*ka, p2 = ub*kb;
#pragma unroll
      for (int o=16;o>=1;o>>=1){
        p1 += __shfl_xor(p1, o, 32);
        p2 += __shfl_xor(p2, o, 32);
      }
      float s1 = p1*pa, s2 = p2*pb;
      size_t mb = (size_t)s*(T_R*T_HD) + (size_t)rt*T_HD;
      float ma = bf2f(mtp[mb + lane]);
      float mv = bf2f(mtp[mb + 64 + lane]);
      float mn1 = fmaxf(m1, s1), mn2 = fmaxf(m2, s2);
      float sc1 = __expf(m1 - mn1), sc2 = __expf(m2 - mn2);
      float w1 = __expf(s1 - mn1), w2 = __expf(s2 - mn2);
      m1 = mn1; m2 = mn2;
      d1 = d1*sc1 + w1; d2 = d2*sc2 + w2;
      a1 = a1*sc1 + w1*ma; a2 = a2*sc2 + w2*mv;
    }
    float i1 = 1.f / fmaxf(d1, 1e-9f);
    float i2 = 1.f / fmaxf(d2, 1e-9f);
    resb[(size_t)dst*T_HD + lane]      = a1 * i1;
    resb[(size_t)dst*T_HD + 64 + lane] = a2 * i2;
  }
}

extern "C" void kernel_launch(void* const* d_in, const int* in_sizes, int n_in,
                              void* d_out, int out_size, void* d_ws, size_t ws_size,
                              hipStream_t stream)
{
  const float* node_feature = (const float*)d_in[0];
  const int* node_type    = (const int*)d_in[1];
  // d_in[2] edge_time: unused by the reference
  const int* edge_index   = (const int*)d_in[3];
  const int* edge_type    = (const int*)d_in[4];
  const float* adapt_w = (const float*)d_in[5];
  const float* adapt_b = (const float*)d_in[6];
  const float* kw = (const float*)d_in[7];
  const float* kb = (const float*)d_in[8];
  const float* qw = (const float*)d_in[9];
  const float* qb = (const float*)d_in[10];
  const float* vw = (const float*)d_in[11];
  const float* vb = (const float*)d_in[12];
  const float* aw = (const float*)d_in[13];
  const float* ab = (const float*)d_in[14];
  const float* rel_pri = (const float*)d_in[15];
  const float* rel_att = (const float*)d_in[16];
  const float* rel_msg = (const float*)d_in[17];
  const float* skipp   = (const float*)d_in[18];

  const int N = in_sizes[1];
  const int E = in_sizes[4];
  const int* srcp = edge_index;
  const int* dstp = edge_index + E;

  char* p = (char*)d_ws;
  auto take = [&](size_t bytes)->char*{
    char* r = p; p += (bytes + 255) & ~(size_t)255; return r;
  };
  float* h0   = (float*)take((size_t)N*T_HD*4);      // 25.6 MB f32 features
  u16*  kB    = (u16*) take((size_t)N*T_HD*2);       // 12.8 MB
  u16*  qB    = (u16*) take((size_t)N*T_HD*2);       // 12.8 MB
  u16*  vB    = (u16*) take((size_t)N*T_HD*2);       // 12.8 MB (contiguous with qB)
  float* resb = (float*)qB;                          // alias qB+vB (dead once qt/mtp built)
  u16*  qt    = (u16*) take((size_t)N*T_R*T_HD*2);   // 64 MB
  u16*  mtp   = (u16*) take((size_t)N*T_R*T_HD*2);   // 64 MB
  int* deg    = (int*) take((size_t)N*4);
  int* rp     = (int*) take(((size_t)N+1)*4);
  int* cur    = (int*) take((size_t)N*4);
  int* packed = (int*) take((size_t)E*4);
  int* tcnt   = (int*) take(256);
  int* toff   = (int*) take(256);
  int* tcur   = (int*) take(256);
  int* tperm  = (int*) take((size_t)N*4);

  hipMemsetAsync(deg, 0, (size_t)N*4, stream);
  hipMemsetAsync(tcnt, 0, 256, stream);
  hipMemsetAsync(tcur, 0, 256, stream);

  int nb_n = (N + 255)/256, nb_e = (E + 255)/256;
  k_hist<<<nb_n, 256, 0, stream>>>(node_type, tcnt, N);
  k_hist<<<nb_e, 256, 0, stream>>>(dstp, deg, E);
  k_toff<<<1, 64, 0, stream>>>(tcnt, toff);
  k_scan<<<1, 1024, 0, stream>>>(deg, rp, N);
  k_scatter_nodes<<<nb_n, 256, 0, stream>>>(node_type, toff, tcur, tperm, N);
  k_copy<<<nb_n, 256, 0, stream>>>(rp, cur, N);
  k_fill_edges<<<nb_e, 256, 0, stream>>>(srcp, dstp, edge_type, cur, packed, E);

  dim3 gg((N + 63)/64, T_NT);
  dim3 gb((N + 63)/64, T_R);
  // adapt: h0 = tanh(node_feature @ adapt_w[t] + adapt_b[t])
  k_typed_gemm<1,0><<<gg, 256, 0, stream>>>(node_feature, tperm, toff, adapt_w, adapt_b, h0, nullptr, nullptr);

  for (int l = 0; l < T_L; ++l){
    size_t wo = (size_t)l * T_NT * T_HD * T_HD;
    size_t bo = (size_t)l * T_NT * T_HD;
    size_t ro = (size_t)l * T_R * T_H * T_DK * T_DK;
    k_typed_gemm<0,1><<<gg, 256, 0, stream>>>(h0, tperm, toff, kw+wo, kb+bo, kB, nullptr, nullptr);
    k_typed_gemm<0,1><<<gg, 256, 0, stream>>>(h0, tperm, toff, qw+wo, qb+bo, qB, nullptr, nullptr);
    k_typed_gemm<0,1><<<gg, 256, 0, stream>>>(h0, tperm, toff, vw+wo, vb+bo, vB, nullptr, nullptr);
    k_blockdiag<1><<<gb, 256, 0, stream>>>(qB, rel_att + ro, qt, N);   // qt[n,r,h,i] = sum_j A[r,h,i,j] q[n,h,j]
    k_blockdiag<0><<<gb, 256, 0, stream>>>(vB, rel_msg + ro, mtp, N);  // mtp[n,r,h,j] = sum_i v[n,h,i] M[r,h,i,j]
    k_edge_attn<<<2048, 256, 0, stream>>>(kB, qt, mtp, rp, packed, rel_pri + (size_t)l*T_R*T_H, resb, N);
    if (l == T_L - 1)
      k_typed_gemm<3,0><<<gg, 256, 0, stream>>>(resb, tperm, toff, aw+wo, ab+bo, d_out, h0, skipp + l*T_NT);
    else
      k_typed_gemm<3,0><<<gg, 256, 0, stream>>>(resb, tperm, toff, aw+wo, ab+bo, h0, h0, skipp + l*T_NT);
  }
}

// Round 3
// 1658.868 us; speedup vs baseline: 1.3259x; 1.3259x over previous
//
#include <hip/hip_runtime.h>

#define T_NT 4
#define T_R  5
#define T_H  4
#define T_DK 32
#define T_HD 128
#define T_L  2

typedef unsigned short u16;

__device__ __forceinline__ float bf2f(u16 u){
  union { float f; unsigned int i; } v; v.i = ((unsigned int)u) << 16; return v.f;
}
__device__ __forceinline__ u16 f2bf(float f){
  union { float f; unsigned int i; } v; v.f = f;
  unsigned int x = v.i;
  return (u16)((x + 0x7fffu + ((x >> 16) & 1u)) >> 16);
}
__device__ __forceinline__ float gelu_f(float x){
  float x3 = x*x*x;
  return 0.5f * x * (1.f + tanhf(0.7978845608028654f * (x + 0.044715f * x3)));
}

// ---------------- CSR / bucket build (LDS-aggregated, line-padded) ----------------
__global__ void k_hist4(const int* __restrict__ key, int* __restrict__ cnt, int n){
  __shared__ int c[T_NT];
  int tid = threadIdx.x;
  if (tid < T_NT) c[tid] = 0;
  __syncthreads();
  int base = blockIdx.x*1024;
#pragma unroll
  for (int j=0;j<4;j++){
    int i = base + tid + j*256;
    if (i < n) atomicAdd(&c[key[i]], 1);
  }
  __syncthreads();
  if (tid < T_NT) atomicAdd(&cnt[tid], c[tid]);
}

__global__ void k_toff(const int* __restrict__ cnt, int* __restrict__ off, int* __restrict__ tcur){
  if (threadIdx.x == 0){
    off[0] = 0;
    for (int t = 0; t < T_NT; ++t) off[t+1] = off[t] + cnt[t];
    for (int t = 0; t < T_NT; ++t) tcur[t] = off[t];
  }
}

__global__ void k_scatter2(const int* __restrict__ nt, int* __restrict__ tcur,
                           int* __restrict__ perm, int n){
  __shared__ int lc[T_NT], lb[T_NT];
  int tid = threadIdx.x;
  if (tid < T_NT) lc[tid] = 0;
  __syncthreads();
  int base = blockIdx.x*1024;
  int t[4], lr[4];
#pragma unroll
  for (int j=0;j<4;j++){
    int i = base + tid + j*256;
    if (i < n){ t[j] = nt[i]; lr[j] = atomicAdd(&lc[t[j]], 1); }
    else t[j] = -1;
  }
  __syncthreads();
  if (tid < T_NT) lb[tid] = atomicAdd(&tcur[tid], lc[tid]);
  __syncthreads();
#pragma unroll
  for (int j=0;j<4;j++){
    if (t[j] >= 0) perm[lb[t[j]] + lr[j]] = base + tid + j*256;
  }
}

// degree histogram with 64B-padded counters; captures per-edge rank
__global__ void k_deg(const int* __restrict__ dstp, int* __restrict__ degp,
                      int* __restrict__ rank, int n){
  int i = blockIdx.x*256 + threadIdx.x;
  if (i < n) rank[i] = atomicAdd(&degp[(size_t)dstp[i] << 4], 1);
}

// single-block scan: thread-serial chunks + 1024-wide LDS scan
__global__ void k_scan2(const int* __restrict__ degp, int* __restrict__ rp, int n){
  __shared__ int buf[1024];
  int tid = threadIdx.x;
  int ch = (n + 1023) >> 10;
  int lo = tid*ch, hi = lo + ch; if (hi > n) hi = n;
  int s = 0;
  for (int j = lo; j < hi; ++j) s += degp[(size_t)j << 4];
  buf[tid] = s;
  __syncthreads();
  for (int off = 1; off < 1024; off <<= 1){
    int add = (tid >= off) ? buf[tid - off] : 0;
    __syncthreads();
    buf[tid] += add;
    __syncthreads();
  }
  int b = (tid == 0) ? 0 : buf[tid-1];
  for (int j = lo; j < hi; ++j){ rp[j] = b; b += degp[(size_t)j << 4]; }
  if (tid == 1023) rp[n] = buf[1023];
}

// atomic-free edge placement using precomputed ranks
__global__ void k_fill2(const int* __restrict__ srcp, const int* __restrict__ dstp,
                        const int* __restrict__ etp, const int* __restrict__ rp,
                        const int* __restrict__ rank, int* __restrict__ packed, int n){
  int i = blockIdx.x*256 + threadIdx.x;
  if (i < n){
    int d = dstp[i];
    packed[rp[d] + rank[i]] = srcp[i] | (etp[i] << 17);   // N=50000 < 2^17
  }
}

// ---------------- per-type gathered GEMM (f32 in, f32 weights, fp32 accum) ----------------
// MODE: 0 plain, 1 tanh epilogue (adapt), 3 gelu-on-input + gated residual (update)
// OB: 1 -> out bf16 (u16), 0 -> out f32
template<int MODE, int OB>
__global__ __launch_bounds__(256)
void k_typed_gemm(const float* __restrict__ X,
                  const int* __restrict__ tperm, const int* __restrict__ toff,
                  const float* __restrict__ W, const float* __restrict__ Bi,
                  void* __restrict__ outv,
                  const float* __restrict__ h_in, const float* __restrict__ skipv)
{
  int t = blockIdx.y;
  int lo = toff[t], cnt = toff[t+1] - lo;
  int base = (int)blockIdx.x * 64;
  if (base >= cnt) return;
  __shared__ float As[64][16];
  __shared__ float Bs[16][128];
  __shared__ int rows_s[64];
  int tid = threadIdx.x;
  if (tid < 64){
    int m = base + tid;
    rows_s[tid] = (m < cnt) ? tperm[lo + m] : -1;
  }
  __syncthreads();
  float acc[8][4];
#pragma unroll
  for (int i=0;i<8;i++){ acc[i][0]=0.f;acc[i][1]=0.f;acc[i][2]=0.f;acc[i][3]=0.f; }
  int ty = tid >> 5, tx = tid & 31;
  const float* Wt = W + (size_t)t * (T_HD*T_HD);
  for (int k0 = 0; k0 < T_HD; k0 += 16){
#pragma unroll
    for (int j=0;j<4;j++){
      int idx = tid + j*256;
      int m = idx >> 4, kk = idx & 15;
      int row = rows_s[m];
      float v = 0.f;
      if (row >= 0){
        v = X[(size_t)row*T_HD + k0 + kk];
        if (MODE == 3) v = gelu_f(v);
      }
      As[m][kk] = v;
    }
#pragma unroll
    for (int j=0;j<8;j++){
      int idx = tid + j*256;
      int kk = idx >> 7, c = idx & 127;
      Bs[kk][c] = Wt[(size_t)(k0+kk)*T_HD + c];
    }
    __syncthreads();
#pragma unroll
    for (int kk=0;kk<16;kk++){
      float4 bv = *(const float4*)&Bs[kk][tx*4];
#pragma unroll
      for (int i=0;i<8;i++){
        float a = As[ty*8+i][kk];
        acc[i][0] += a*bv.x; acc[i][1] += a*bv.y; acc[i][2] += a*bv.z; acc[i][3] += a*bv.w;
      }
    }
    __syncthreads();
  }
  float sk = 0.f;
  if (MODE == 3) sk = 1.f / (1.f + __expf(-skipv[t]));
#pragma unroll
  for (int i=0;i<8;i++){
    int m = ty*8 + i;
    int row = rows_s[m];
    if (row < 0) continue;
#pragma unroll
    for (int q=0;q<4;q++){
      int c = tx*4 + q;
      float vv = acc[i][q] + Bi[t*T_HD + c];
      if (MODE == 1) vv = tanhf(vv);
      if (MODE == 3) vv = vv*sk + h_in[(size_t)row*T_HD + c]*(1.f - sk);
      if (OB) ((u16*)outv)[(size_t)row*T_HD + c] = f2bf(vv);
      else    ((float*)outv)[(size_t)row*T_HD + c] = vv;
    }
  }
}

// ---------------- per-node block-diagonal transform ----------------
// TR=1 (qt): out[n,r,h,i] = sum_j X[n,h*32+j] * Wg[r,h,i,j]
// TR=0 (mtp): out[n,r,h,j] = sum_i X[n,h*32+i] * Wg[r,h,i,j]
template<int TR>
__global__ __launch_bounds__(256)
void k_blockdiag(const u16* __restrict__ X, const float* __restrict__ Wg,
                 u16* __restrict__ Y, int n)
{
  int r = blockIdx.y;
  int base = (int)blockIdx.x * 64;
  if (base >= n) return;
  __shared__ float Xs[64][T_H][33];
  __shared__ float Ws[T_H * 1032];   // per-head stride 1032 (bank spread)
  int tid = threadIdx.x;
  for (int idx = tid; idx < T_H*T_DK*T_DK; idx += 256){
    int o = idx & 31, c = (idx >> 5) & 31, h = idx >> 10;
    float wv;
    if (TR) wv = Wg[(((size_t)r*T_H + h)*T_DK + o)*T_DK + c];
    else    wv = Wg[(((size_t)r*T_H + h)*T_DK + c)*T_DK + o];
    Ws[h*1032 + c*32 + o] = wv;
  }
  for (int idx = tid; idx < 64*T_HD; idx += 256){
    int mm = idx >> 7, cc = idx & 127;
    int row = base + mm;
    Xs[mm][cc >> 5][cc & 31] = (row < n) ? bf2f(X[(size_t)row*T_HD + cc]) : 0.f;
  }
  __syncthreads();
  int ty = tid >> 5, tx = tid & 31;
  int h = tx >> 3, ob = tx & 7;
  float acc[8][4];
#pragma unroll
  for (int i=0;i<8;i++){ acc[i][0]=0.f;acc[i][1]=0.f;acc[i][2]=0.f;acc[i][3]=0.f; }
  const float* Wh = &Ws[h*1032];
#pragma unroll
  for (int c=0;c<T_DK;c++){
    float w0 = Wh[c*32 + ob];
    float w1 = Wh[c*32 + ob + 8];
    float w2 = Wh[c*32 + ob + 16];
    float w3 = Wh[c*32 + ob + 24];
#pragma unroll
    for (int i=0;i<8;i++){
      float x = Xs[ty*8+i][h][c];
      acc[i][0] += x*w0; acc[i][1] += x*w1; acc[i][2] += x*w2; acc[i][3] += x*w3;
    }
  }
#pragma unroll
  for (int i=0;i<8;i++){
    int row = base + ty*8 + i;
    if (row < n){
      size_t rb = (size_t)row*(T_R*T_HD) + (size_t)r*T_HD + h*32 + ob;
      Y[rb]      = f2bf(acc[i][0]);
      Y[rb + 8]  = f2bf(acc[i][1]);
      Y[rb + 16] = f2bf(acc[i][2]);
      Y[rb + 24] = f2bf(acc[i][3]);
    }
  }
}

// ---------------- per-dst edge attention (one wave per dst, online softmax) ----------------
__global__ __launch_bounds__(256)
void k_edge_attn(const u16* __restrict__ kB, const u16* __restrict__ qt,
                 const u16* __restrict__ mtp, const int* __restrict__ rp,
                 const int* __restrict__ packed, const float* __restrict__ pri,
                 float* __restrict__ resb, int n)
{
  int lane = threadIdx.x & 63;
  int wid = (int)blockIdx.x * (blockDim.x >> 6) + (threadIdx.x >> 6);
  int nw = (int)gridDim.x * (blockDim.x >> 6);
  int h1 = lane >> 5;           // head of first half: 0/1; second half head = h1+2
  const float isd = 0.17677669529663687f;
  float pr1[T_R], pr2[T_R];
#pragma unroll
  for (int r=0;r<T_R;r++){
    pr1[r] = pri[r*T_H + h1] * isd;
    pr2[r] = pri[r*T_H + h1 + 2] * isd;
  }
  for (int dst = wid; dst < n; dst += nw){
    int e0 = rp[dst], e1 = rp[dst+1];
    size_t qbase = (size_t)dst * (T_R*T_HD);
    float u1[T_R], u2[T_R];
#pragma unroll
    for (int r=0;r<T_R;r++){
      u1[r] = bf2f(qt[qbase + r*T_HD + lane]);
      u2[r] = bf2f(qt[qbase + r*T_HD + 64 + lane]);
    }
    float m1=-INFINITY, m2=-INFINITY, d1=0.f, d2=0.f, a1=0.f, a2=0.f;
    for (int ei=e0; ei<e1; ++ei){
      int pk = packed[ei];
      int s = pk & 131071;
      int rt = pk >> 17;
      float ka = bf2f(kB[(size_t)s*T_HD + lane]);
      float kb = bf2f(kB[(size_t)s*T_HD + 64 + lane]);
      float ua, ub, pa, pb;
      switch(rt){
        case 0: ua=u1[0]; ub=u2[0]; pa=pr1[0]; pb=pr2[0]; break;
        case 1: ua=u1[1]; ub=u2[1]; pa=pr1[1]; pb=pr2[1]; break;
        case 2: ua=u1[2]; ub=u2[2]; pa=pr1[2]; pb=pr2[2]; break;
        case 3: ua=u1[3]; ub=u2[3]; pa=pr1[3]; pb=pr2[3]; break;
        default:ua=u1[4]; ub=u2[4]; pa=pr1[4]; pb=pr2[4]; break;
      }
      float p1 = ua*ka, p2 = ub*kb;
#pragma unroll
      for (int o=16;o>=1;o>>=1){
        p1 += __shfl_xor(p1, o, 32);
        p2 += __shfl_xor(p2, o, 32);
      }
      float s1 = p1*pa, s2 = p2*pb;
      size_t mb = (size_t)s*(T_R*T_HD) + (size_t)rt*T_HD;
      float ma = bf2f(mtp[mb + lane]);
      float mv = bf2f(mtp[mb + 64 + lane]);
      float mn1 = fmaxf(m1, s1), mn2 = fmaxf(m2, s2);
      float sc1 = __expf(m1 - mn1), sc2 = __expf(m2 - mn2);
      float w1 = __expf(s1 - mn1), w2 = __expf(s2 - mn2);
      m1 = mn1; m2 = mn2;
      d1 = d1*sc1 + w1; d2 = d2*sc2 + w2;
      a1 = a1*sc1 + w1*ma; a2 = a2*sc2 + w2*mv;
    }
    float i1 = 1.f / fmaxf(d1, 1e-9f);
    float i2 = 1.f / fmaxf(d2, 1e-9f);
    resb[(size_t)dst*T_HD + lane]      = a1 * i1;
    resb[(size_t)dst*T_HD + 64 + lane] = a2 * i2;
  }
}

extern "C" void kernel_launch(void* const* d_in, const int* in_sizes, int n_in,
                              void* d_out, int out_size, void* d_ws, size_t ws_size,
                              hipStream_t stream)
{
  const float* node_feature = (const float*)d_in[0];
  const int* node_type    = (const int*)d_in[1];
  // d_in[2] edge_time: unused by the reference
  const int* edge_index   = (const int*)d_in[3];
  const int* edge_type    = (const int*)d_in[4];
  const float* adapt_w = (const float*)d_in[5];
  const float* adapt_b = (const float*)d_in[6];
  const float* kw = (const float*)d_in[7];
  const float* kb = (const float*)d_in[8];
  const float* qw = (const float*)d_in[9];
  const float* qb = (const float*)d_in[10];
  const float* vw = (const float*)d_in[11];
  const float* vb = (const float*)d_in[12];
  const float* aw = (const float*)d_in[13];
  const float* ab = (const float*)d_in[14];
  const float* rel_pri = (const float*)d_in[15];
  const float* rel_att = (const float*)d_in[16];
  const float* rel_msg = (const float*)d_in[17];
  const float* skipp   = (const float*)d_in[18];

  const int N = in_sizes[1];
  const int E = in_sizes[4];
  const int* srcp = edge_index;
  const int* dstp = edge_index + E;

  char* p = (char*)d_ws;
  auto take = [&](size_t bytes)->char*{
    char* r = p; p += (bytes + 255) & ~(size_t)255; return r;
  };
  float* h0   = (float*)take((size_t)N*T_HD*4);      // 25.6 MB f32 features
  u16*  kB    = (u16*) take((size_t)N*T_HD*2);       // 12.8 MB
  u16*  qB    = (u16*) take((size_t)N*T_HD*2);       // 12.8 MB
  u16*  vB    = (u16*) take((size_t)N*T_HD*2);       // 12.8 MB (contiguous with qB)
  float* resb = (float*)qB;                          // alias qB+vB (dead once qt/mtp built)
  u16*  qt    = (u16*) take((size_t)N*T_R*T_HD*2);   // 64 MB
  u16*  mtp   = (u16*) take((size_t)N*T_R*T_HD*2);   // 64 MB
  int* degp   = (int*) take((size_t)N*16*4);         // 3.2 MB line-padded counters
  int* rp     = (int*) take(((size_t)N+1)*4);
  int* rank   = (int*) take((size_t)E*4);
  int* packed = (int*) take((size_t)E*4);
  int* tcnt   = (int*) take(256);
  int* toff   = (int*) take(256);
  int* tcur   = (int*) take(256);
  int* tperm  = (int*) take((size_t)N*4);

  hipMemsetAsync(degp, 0, (size_t)N*16*4, stream);
  hipMemsetAsync(tcnt, 0, 256, stream);

  int nb_n4 = (N + 1023)/1024, nb_e = (E + 255)/256;
  k_hist4<<<nb_n4, 256, 0, stream>>>(node_type, tcnt, N);
  k_deg<<<nb_e, 256, 0, stream>>>(dstp, degp, rank, E);
  k_toff<<<1, 64, 0, stream>>>(tcnt, toff, tcur);
  k_scan2<<<1, 1024, 0, stream>>>(degp, rp, N);
  k_scatter2<<<nb_n4, 256, 0, stream>>>(node_type, tcur, tperm, N);
  k_fill2<<<nb_e, 256, 0, stream>>>(srcp, dstp, edge_type, rp, rank, packed, E);

  dim3 gg((N + 63)/64, T_NT);
  dim3 gb((N + 63)/64, T_R);
  // adapt: h0 = tanh(node_feature @ adapt_w[t] + adapt_b[t])
  k_typed_gemm<1,0><<<gg, 256, 0, stream>>>(node_feature, tperm, toff, adapt_w, adapt_b, h0, nullptr, nullptr);

  for (int l = 0; l < T_L; ++l){
    size_t wo = (size_t)l * T_NT * T_HD * T_HD;
    size_t bo = (size_t)l * T_NT * T_HD;
    size_t ro = (size_t)l * T_R * T_H * T_DK * T_DK;
    k_typed_gemm<0,1><<<gg, 256, 0, stream>>>(h0, tperm, toff, kw+wo, kb+bo, kB, nullptr, nullptr);
    k_typed_gemm<0,1><<<gg, 256, 0, stream>>>(h0, tperm, toff, qw+wo, qb+bo, qB, nullptr, nullptr);
    k_typed_gemm<0,1><<<gg, 256, 0, stream>>>(h0, tperm, toff, vw+wo, vb+bo, vB, nullptr, nullptr);
    k_blockdiag<1><<<gb, 256, 0, stream>>>(qB, rel_att + ro, qt, N);   // qt[n,r,h,i] = sum_j A[r,h,i,j] q[n,h,j]
    k_blockdiag<0><<<gb, 256, 0, stream>>>(vB, rel_msg + ro, mtp, N);  // mtp[n,r,h,j] = sum_i v[n,h,i] M[r,h,i,j]
    k_edge_attn<<<2048, 256, 0, stream>>>(kB, qt, mtp, rp, packed, rel_pri + (size_t)l*T_R*T_H, resb, N);
    if (l == T_L - 1)
      k_typed_gemm<3,0><<<gg, 256, 0, stream>>>(resb, tperm, toff, aw+wo, ab+bo, d_out, h0, skipp + l*T_NT);
    else
      k_typed_gemm<3,0><<<gg, 256, 0, stream>>>(resb, tperm, toff, aw+wo, ab+bo, h0, h0, skipp + l*T_NT);
  }
}